// Round 3
// baseline (214.621 us; speedup 1.0000x reference)
//
#include <hip/hip_runtime.h>

// Problem constants
#define NB 128
#define NL 1024
#define NE 512
#define NA 512
#define ND 512

typedef __attribute__((ext_vector_type(8))) short short8;
typedef __attribute__((ext_vector_type(4))) float f32x4;

static __device__ __forceinline__ unsigned short f2bf(float f) {
  unsigned int u = __float_as_uint(f);
  u += 0x7FFF + ((u >> 16) & 1);   // round-to-nearest-even
  return (unsigned short)(u >> 16);
}

// ---------------------------------------------------------------------------
// Kernel 1 (merged): blocks 0..63 pack W_enc -> bf16 MFMA B-fragment order;
// blocks 64..191 compute att2[b][a] = dec[b]@W_dec[:,a] + b_dec[a] + b_enc[a].
// Bpack layout: [nf=0..31][ki=0..15][lane=0..63][j=0..7]
//   lane l holds B[k][n], k = ki*32 + (l>>4)*8 + j, n = nf*16 + (l&15)
__global__ void k_prep(const float* __restrict__ W_enc,
                       unsigned short* __restrict__ Bpack,
                       const float* __restrict__ dec,
                       const float* __restrict__ Wdec,
                       const float* __restrict__ b_enc,
                       const float* __restrict__ b_dec,
                       float* __restrict__ att2) {
  int blk = blockIdx.x;
  int tid = threadIdx.x;  // 512
  if (blk < 64) {
    int t = blk * 512 + tid;  // 0..32767
    int lane = t & 63;
    int rest = t >> 6;
    int ki = rest & 15;
    int nf = rest >> 4;
    int col = nf * 16 + (lane & 15);
    int kbase = ki * 32 + (lane >> 4) * 8;
    short8 v;
#pragma unroll
    for (int j = 0; j < 8; ++j)
      v[j] = (short)f2bf(W_enc[(kbase + j) * NA + col]);
    *reinterpret_cast<short8*>(Bpack + (long)t * 8) = v;
  } else {
    int b = blk - 64;
    int a = tid;
    float acc = b_enc[a] + b_dec[a];
    const float* drow = dec + b * ND;
#pragma unroll 4
    for (int d = 0; d < ND; ++d)
      acc += drow[d] * Wdec[d * NA + a];
    att2[b * NA + a] = acc;
  }
}

// ---------------------------------------------------------------------------
// Kernel 2: fused scores GEMM. 512 thr (8 waves), BM=64 rows.
// Wave w computes all 64 rows x cols [w*64, w*64+64) -> acc[4][4] (64 VGPR).
// A staged in LDS bf16 (XOR swizzle); B frags from L2-resident Bpack with a
// depth-2 register prefetch (two NAMED buffers -> static indices, no scratch).
// Epilogue: relu(acc+att2)*W_full reduced over cols -> att[m] (b_full dropped).
__global__ __launch_bounds__(512, 4) void k_scores(
    const float* __restrict__ enc, const unsigned short* __restrict__ Bpack,
    const float* __restrict__ att2, const float* __restrict__ wfull,
    float* __restrict__ att) {
  extern __shared__ char smem[];
  float* a2row = (float*)(smem + 65536);          // 512 f
  float* wf    = (float*)(smem + 67584);          // 512 f
  float* red   = (float*)(smem + 69632);          // 8 waves x 64 rows

  const int t = threadIdx.x;
  const int blk = blockIdx.x;
  const long row0 = (long)blk * 64;
  const int b = blk >> 4;   // 64*16 = 1024 rows per batch

  // ---- stage A: 64 rows x 512 cols fp32 -> bf16, swizzled ----
  {
    const float* src = enc + row0 * NE;
#pragma unroll
    for (int i = 0; i < 8; ++i) {
      int c = i * 512 + t;          // chunk id 0..4095, 8 floats each
      int row = c >> 6;
      int colb = (c & 63) * 16;     // byte offset within row (8 bf16 = 16B)
      const float4* p = reinterpret_cast<const float4*>(src + (long)c * 8);
      float4 x0 = p[0];
      float4 x1 = p[1];
      short8 o;
      o[0] = (short)f2bf(x0.x); o[1] = (short)f2bf(x0.y);
      o[2] = (short)f2bf(x0.z); o[3] = (short)f2bf(x0.w);
      o[4] = (short)f2bf(x1.x); o[5] = (short)f2bf(x1.y);
      o[6] = (short)f2bf(x1.z); o[7] = (short)f2bf(x1.w);
      int byte = (row * 1024 + colb) ^ ((row & 7) << 4);
      *reinterpret_cast<short8*>(smem + byte) = o;
    }
    if (t < 256) {
      a2row[t]       = att2[b * NA + t];
      a2row[t + 256] = att2[b * NA + t + 256];
    } else {
      int u = t - 256;
      wf[u]          = wfull[u];
      wf[u + 256]    = wfull[u + 256];
    }
  }
  __syncthreads();

  const int lane = t & 63;
  const int wave = t >> 6;
  const int l15 = lane & 15;
  const int lq = lane >> 4;

  // Wave w's 4 column-fragments: nf = wave*4 + cf. Frag (cf,ki) at
  // short8 index ((wave*4+cf)*16 + ki)*64 + lane.
  const short8* bp_w = reinterpret_cast<const short8*>(Bpack)
                       + (size_t)wave * 4 * 16 * 64;

  f32x4 acc[4][4];
#pragma unroll
  for (int rt = 0; rt < 4; ++rt)
#pragma unroll
    for (int cf = 0; cf < 4; ++cf) acc[rt][cf] = (f32x4){0.f, 0.f, 0.f, 0.f};

  short8 bA[4], bB[4];
#pragma unroll
  for (int cf = 0; cf < 4; ++cf) bA[cf] = bp_w[(cf * 16 + 0) * 64 + lane];
#pragma unroll
  for (int cf = 0; cf < 4; ++cf) bB[cf] = bp_w[(cf * 16 + 1) * 64 + lane];

#pragma unroll
  for (int kk = 0; kk < 16; kk += 2) {
    // consume bA (ki = kk)
#pragma unroll
    for (int rt = 0; rt < 4; ++rt) {
      const int ar = rt * 16 + l15;
      const int abyte = (ar * 1024 + kk * 64 + lq * 16) ^ ((ar & 7) << 4);
      short8 av = *reinterpret_cast<const short8*>(smem + abyte);
#pragma unroll
      for (int cf = 0; cf < 4; ++cf)
        acc[rt][cf] =
            __builtin_amdgcn_mfma_f32_16x16x32_bf16(av, bA[cf], acc[rt][cf], 0, 0, 0);
    }
    if (kk + 2 < 16) {
#pragma unroll
      for (int cf = 0; cf < 4; ++cf) bA[cf] = bp_w[(cf * 16 + kk + 2) * 64 + lane];
    }
    // consume bB (ki = kk+1)
#pragma unroll
    for (int rt = 0; rt < 4; ++rt) {
      const int ar = rt * 16 + l15;
      const int abyte = (ar * 1024 + (kk + 1) * 64 + lq * 16) ^ ((ar & 7) << 4);
      short8 av = *reinterpret_cast<const short8*>(smem + abyte);
#pragma unroll
      for (int cf = 0; cf < 4; ++cf)
        acc[rt][cf] =
            __builtin_amdgcn_mfma_f32_16x16x32_bf16(av, bB[cf], acc[rt][cf], 0, 0, 0);
    }
    if (kk + 3 < 16) {
#pragma unroll
      for (int cf = 0; cf < 4; ++cf) bB[cf] = bp_w[(cf * 16 + kk + 3) * 64 + lane];
    }
  }

  // Epilogue: relu + project + reduce over this wave's 64 cols.
  // C layout: row = rt*16 + lq*4 + r, col = wave*64 + cf*16 + l15.
  float partial[4][4];
#pragma unroll
  for (int rt = 0; rt < 4; ++rt)
#pragma unroll
    for (int r = 0; r < 4; ++r) partial[rt][r] = 0.f;

#pragma unroll
  for (int cf = 0; cf < 4; ++cf) {
    int col = wave * 64 + cf * 16 + l15;
    float a2 = a2row[col];
    float w = wf[col];
#pragma unroll
    for (int rt = 0; rt < 4; ++rt)
#pragma unroll
      for (int r = 0; r < 4; ++r) {
        float v = acc[rt][cf][r] + a2;
        partial[rt][r] += fmaxf(v, 0.f) * w;
      }
  }
#pragma unroll
  for (int rt = 0; rt < 4; ++rt)
#pragma unroll
    for (int r = 0; r < 4; ++r) {
      float p = partial[rt][r];
      p += __shfl_xor(p, 1);
      p += __shfl_xor(p, 2);
      p += __shfl_xor(p, 4);
      p += __shfl_xor(p, 8);
      partial[rt][r] = p;
    }
  if (l15 == 0) {
#pragma unroll
    for (int rt = 0; rt < 4; ++rt)
#pragma unroll
      for (int r = 0; r < 4; ++r)
        red[wave * 64 + rt * 16 + lq * 4 + r] = partial[rt][r];
  }
  __syncthreads();
  if (t < 64) {
    float s = 0.f;
#pragma unroll
    for (int w = 0; w < 8; ++w) s += red[w * 64 + t];
    att[row0 + t] = s;
  }
}

// ---------------------------------------------------------------------------
// Kernel 3: softmax over L=1024 per batch row. alpha written to d_out.
__global__ void k_softmax(const float* __restrict__ att,
                          float* __restrict__ alpha) {
  int b = blockIdx.x;
  int t = threadIdx.x;  // 256
  const float* row = att + b * NL;
  float v0 = row[t], v1 = row[t + 256], v2 = row[t + 512], v3 = row[t + 768];
  float m = fmaxf(fmaxf(v0, v1), fmaxf(v2, v3));
#pragma unroll
  for (int off = 1; off < 64; off <<= 1) m = fmaxf(m, __shfl_xor(m, off));
  __shared__ float rm[4];
  int lane = t & 63, w = t >> 6;
  if (lane == 0) rm[w] = m;
  __syncthreads();
  m = fmaxf(fmaxf(rm[0], rm[1]), fmaxf(rm[2], rm[3]));
  float e0 = expf(v0 - m), e1 = expf(v1 - m), e2 = expf(v2 - m), e3 = expf(v3 - m);
  float s = e0 + e1 + e2 + e3;
#pragma unroll
  for (int off = 1; off < 64; off <<= 1) s += __shfl_xor(s, off);
  __shared__ float rs[4];
  if (lane == 0) rs[w] = s;
  __syncthreads();
  s = rs[0] + rs[1] + rs[2] + rs[3];
  float inv = 1.f / s;
  float* arow = alpha + b * NL;
  arow[t] = e0 * inv;
  arow[t + 256] = e1 * inv;
  arow[t + 512] = e2 * inv;
  arow[t + 768] = e3 * inv;
}

// ---------------------------------------------------------------------------
// Kernel 4: partial weighted sum. Grid = 128 b * 16 l-chunks, 128 threads.
// Thread owns 4 e-cols (float4), 64 l-iterations per chunk.
__global__ void k_wpart(const float* __restrict__ enc,
                        const float* __restrict__ alpha,
                        float* __restrict__ part) {
  int bid = blockIdx.x;          // 0..2047
  int b = bid >> 4, lc = bid & 15;
  int t = threadIdx.x;           // 0..127
  const float* base = enc + ((long)b * NL + lc * 64) * NE;
  const float* al = alpha + b * NL + lc * 64;
  float4 s = {0.f, 0.f, 0.f, 0.f};
#pragma unroll 4
  for (int l = 0; l < 64; ++l) {
    float a = al[l];
    const float4 x = *reinterpret_cast<const float4*>(base + (long)l * NE + t * 4);
    s.x += a * x.x;
    s.y += a * x.y;
    s.z += a * x.z;
    s.w += a * x.w;
  }
  *reinterpret_cast<float4*>(part + (long)bid * NE + t * 4) = s;
}

// ---------------------------------------------------------------------------
// Kernel 5: reduce 16 l-chunk partials -> weighted [B,E] into d_out.
__global__ void k_wreduce(const float* __restrict__ part,
                          float* __restrict__ outw) {
  int g = blockIdx.x * 256 + threadIdx.x;  // 0..65535
  int b = g >> 9, e = g & 511;
  float s = 0.f;
#pragma unroll
  for (int lc = 0; lc < 16; ++lc) s += part[(long)(b * 16 + lc) * NE + e];
  outw[g] = s;
}

// ---------------------------------------------------------------------------
extern "C" void kernel_launch(void* const* d_in, const int* in_sizes, int n_in,
                              void* d_out, int out_size, void* d_ws, size_t ws_size,
                              hipStream_t stream) {
  const float* enc    = (const float*)d_in[0];  // [B,L,E]
  const float* dec    = (const float*)d_in[1];  // [B,D]
  const float* W_enc  = (const float*)d_in[2];  // [E,A]
  const float* b_enc  = (const float*)d_in[3];  // [A]
  const float* W_dec  = (const float*)d_in[4];  // [D,A]
  const float* b_dec  = (const float*)d_in[5];  // [A]
  const float* W_full = (const float*)d_in[6];  // [A]
  // d_in[7] = b_full: cancels in softmax, unused.

  float* out = (float*)d_out;
  float* weighted = out;                 // [B,E] = 65536
  float* alpha = out + NB * NE;          // [B,L] = 131072

  char* ws = (char*)d_ws;
  float* att2          = (float*)ws;                                   // 256 KB
  unsigned short* Bpk  = (unsigned short*)(ws + (256 << 10));          // 512 KB
  float* att           = (float*)(ws + (768 << 10));                   // 512 KB
  float* part          = (float*)(ws + (1280 << 10));                  // 4 MB

  hipLaunchKernelGGL(k_prep, dim3(192), dim3(512), 0, stream,
                     W_enc, Bpk, dec, W_dec, b_enc, b_dec, att2);
  hipLaunchKernelGGL(k_scores, dim3((NB * NL) / 64), dim3(512), 71680, stream,
                     enc, Bpk, att2, W_full, att);
  hipLaunchKernelGGL(k_softmax, dim3(NB), dim3(256), 0, stream, att, alpha);
  hipLaunchKernelGGL(k_wpart, dim3(NB * 16), dim3(128), 0, stream, enc, alpha, part);
  hipLaunchKernelGGL(k_wreduce, dim3(NB * NE / 256), dim3(256), 0, stream, part, weighted);
}